// Round 1
// baseline (584.143 us; speedup 1.0000x reference)
//
#include <hip/hip_runtime.h>

#define VV 50000
#define DD 300
#define KK 50
#define BB 32
#define SS 8192
#define NN 128
#define LL 64
#define G  4          // segments per block
#define NTHREADS 320  // 5 waves

__global__ __launch_bounds__(NTHREADS) void topic_fused(
    const float* __restrict__ emb,        // [V,D]
    const float* __restrict__ M_w,        // [D,D]
    const float* __restrict__ W_w,        // [K,D]
    const float* __restrict__ T_w,        // [D,K]
    const int*   __restrict__ tokens,     // [B,S]
    const int*   __restrict__ seg_starts, // [B,N]
    const int*   __restrict__ seg_lens,   // [B,N]
    float* __restrict__ out_y,            // [B*N, D]
    float* __restrict__ out_z,            // [B*N, D]
    float* __restrict__ out_p,            // [B*N, K]
    float* __restrict__ out_r)            // [B*N, D]
{
    __shared__ int   tok_s[G][LL];
    __shared__ int   len_s[G];
    __shared__ int   base_s[G];
    __shared__ float y_s[G][DD];
    __shared__ float u_s[G][DD];
    __shared__ float esc_s[G][LL];   // scores, then alpha
    __shared__ float z_s[G][DD];
    __shared__ float p_s[G][KK];

    const int tid  = threadIdx.x;
    const int wave = tid >> 6;
    const int lane = tid & 63;
    const int seg0 = blockIdx.x * G;
    const int d    = tid;            // owned feature dim, active if d < DD

    // ---- phase 0: segment metadata ----
    if (tid < G) {
        int idx = seg0 + tid;
        int b   = idx >> 7;          // N = 128
        len_s[tid]  = seg_lens[idx];
        base_s[tid] = b * SS + seg_starts[idx];
    }
    __syncthreads();

    // ---- phase 1: token gather (wave g loads segment g's 64 tokens) ----
    if (wave < G) {
        tok_s[wave][lane] = tokens[base_s[wave] + lane];
    }
    __syncthreads();

    // ---- phase 2: y = masked mean of embedding rows ----
    for (int g = 0; g < G; ++g) {
        const int len = len_s[g];
        if (d < DD) {
            float acc = 0.f;
            #pragma unroll 4
            for (int l = 0; l < len; ++l) {
                acc += emb[(size_t)tok_s[g][l] * DD + d];
            }
            const float y = acc / (float)len;
            y_s[g][d] = y;
            out_y[(size_t)(seg0 + g) * DD + d] = y;
        }
    }
    __syncthreads();

    // ---- phase 3: u[d] = sum_e M_w[e,d] * y[e]  (shared M_w stream, 4x reuse) ----
    if (d < DD) {
        float ug[G] = {0.f, 0.f, 0.f, 0.f};
        #pragma unroll 4
        for (int e = 0; e < DD; ++e) {
            const float m = M_w[(size_t)e * DD + d];
            #pragma unroll
            for (int g = 0; g < G; ++g) ug[g] += m * y_s[g][e];
        }
        #pragma unroll
        for (int g = 0; g < G; ++g) u_s[g][d] = ug[g];
    }
    __syncthreads();

    // ---- phase 4: esc[l] = dot(emb_row_l, u)  (wave-per-row) ----
    for (int j = wave; j < G * LL; j += NTHREADS / 64) {
        const int g = j >> 6;        // LL = 64
        const int l = j & 63;
        if (l < len_s[g]) {
            const float* row = emb + (size_t)tok_s[g][l] * DD;
            float acc = 0.f;
            for (int c = lane; c < DD; c += 64) acc += row[c] * u_s[g][c];
            #pragma unroll
            for (int m = 32; m; m >>= 1) acc += __shfl_xor(acc, m, 64);
            if (lane == 0) esc_s[g][l] = acc;
        }
    }
    __syncthreads();

    // ---- phase 5: masked softmax over l (wave g handles segment g) ----
    if (wave < G) {
        const int len = len_s[wave];
        const float v = (lane < len) ? esc_s[wave][lane] : -INFINITY;
        float mx = v;
        #pragma unroll
        for (int m = 32; m; m >>= 1) mx = fmaxf(mx, __shfl_xor(mx, m, 64));
        const float e = (lane < len) ? __expf(v - mx) : 0.f;
        float sum = e;
        #pragma unroll
        for (int m = 32; m; m >>= 1) sum += __shfl_xor(sum, m, 64);
        esc_s[wave][lane] = e / sum;      // alpha (0 for padded lanes)
    }
    __syncthreads();

    // ---- phase 6: z[d] = sum_l alpha[l] * emb_row_l[d] ----
    for (int g = 0; g < G; ++g) {
        const int len = len_s[g];
        if (d < DD) {
            float acc = 0.f;
            #pragma unroll 4
            for (int l = 0; l < len; ++l) {
                acc += esc_s[g][l] * emb[(size_t)tok_s[g][l] * DD + d];
            }
            z_s[g][d] = acc;
            out_z[(size_t)(seg0 + g) * DD + d] = acc;
        }
    }
    __syncthreads();

    // ---- phase 7: raw scores s[g][k] = dot(z_g, W_w[k]) (wave-per-(g,k)) ----
    for (int j = wave; j < G * KK; j += NTHREADS / 64) {
        const int g = j / KK;
        const int k = j % KK;
        const float* row = W_w + (size_t)k * DD;
        float acc = 0.f;
        for (int c = lane; c < DD; c += 64) acc += row[c] * z_s[g][c];
        #pragma unroll
        for (int m = 32; m; m >>= 1) acc += __shfl_xor(acc, m, 64);
        if (lane == 0) p_s[g][k] = acc;
    }
    __syncthreads();

    // ---- phase 8: softmax over k; write p ----
    if (wave < G) {
        const float v = (lane < KK) ? p_s[wave][lane] : -INFINITY;
        float mx = v;
        #pragma unroll
        for (int m = 32; m; m >>= 1) mx = fmaxf(mx, __shfl_xor(mx, m, 64));
        const float e = (lane < KK) ? __expf(v - mx) : 0.f;
        float sum = e;
        #pragma unroll
        for (int m = 32; m; m >>= 1) sum += __shfl_xor(sum, m, 64);
        if (lane < KK) {
            const float p = e / sum;
            p_s[wave][lane] = p;
            out_p[(size_t)(seg0 + wave) * KK + lane] = p;
        }
    }
    __syncthreads();

    // ---- phase 9: r[d] = sum_k p[k] * T_w[d,k] ----
    for (int g = 0; g < G; ++g) {
        if (d < DD) {
            const float* trow = T_w + (size_t)d * KK;
            float acc = 0.f;
            #pragma unroll
            for (int k = 0; k < KK; ++k) acc += p_s[g][k] * trow[k];
            out_r[(size_t)(seg0 + g) * DD + d] = acc;
        }
    }
}

extern "C" void kernel_launch(void* const* d_in, const int* in_sizes, int n_in,
                              void* d_out, int out_size, void* d_ws, size_t ws_size,
                              hipStream_t stream) {
    const float* emb        = (const float*)d_in[0];
    const float* M_w        = (const float*)d_in[1];
    const float* W_w        = (const float*)d_in[2];
    const float* T_w        = (const float*)d_in[3];
    const int*   tokens     = (const int*)d_in[4];
    const int*   seg_starts = (const int*)d_in[5];
    const int*   seg_lens   = (const int*)d_in[6];

    float* out   = (float*)d_out;
    float* out_y = out;                                   // [B*N*D]
    float* out_z = out + (size_t)BB * NN * DD;            // [B*N*D]
    float* out_p = out + (size_t)2 * BB * NN * DD;        // [B*N*K]
    float* out_r = out + (size_t)2 * BB * NN * DD + (size_t)BB * NN * KK;

    dim3 grid(BB * NN / G);
    dim3 block(NTHREADS);
    hipLaunchKernelGGL(topic_fused, grid, block, 0, stream,
                       emb, M_w, W_w, T_w, tokens, seg_starts, seg_lens,
                       out_y, out_z, out_p, out_r);
}

// Round 2
// 318.647 us; speedup vs baseline: 1.8332x; 1.8332x over previous
//
#include <hip/hip_runtime.h>

#define VV 50000
#define DD 300
#define KK 50
#define BB 32
#define SS 8192
#define NN 128
#define LL 64
#define NT 320        // 5 waves

#define TM 16         // rows per block in the u-GEMM

__device__ __forceinline__ float wave_sum(float v) {
    #pragma unroll
    for (int m = 32; m; m >>= 1) v += __shfl_xor(v, m, 64);
    return v;
}
__device__ __forceinline__ float wave_max(float v) {
    #pragma unroll
    for (int m = 32; m; m >>= 1) v = fmaxf(v, __shfl_xor(v, m, 64));
    return v;
}

// ---------------- K1: y = masked mean of gathered embedding rows ----------------
__global__ __launch_bounds__(NT) void k_y(
    const float* __restrict__ emb,
    const int*   __restrict__ tokens,
    const int*   __restrict__ seg_starts,
    const int*   __restrict__ seg_lens,
    float* __restrict__ out_y)
{
    __shared__ int tok_s[LL];
    const int tid = threadIdx.x;
    const int seg = blockIdx.x;
    const int b   = seg >> 7;                 // N = 128
    const int start = seg_starts[seg];        // uniform -> scalar load
    const int len   = seg_lens[seg];

    if (tid < LL) tok_s[tid] = tokens[b * SS + start + tid];
    __syncthreads();

    if (tid < DD) {
        float acc = 0.f;
        #pragma unroll 4
        for (int l = 0; l < len; ++l)
            acc += emb[(size_t)tok_s[l] * DD + tid];
        out_y[(size_t)seg * DD + tid] = acc / (float)len;
    }
}

// ---------------- K2: u[seg,d] = sum_e y[seg,e] * M_w[e,d]  (TM rows/block) ----------------
__global__ __launch_bounds__(NT) void k_u(
    const float* __restrict__ y,      // [4096, D]
    const float* __restrict__ M_w,    // [D, D]
    float* __restrict__ u)            // [4096, D]
{
    __shared__ float y_s[TM * DD];    // 19.2 KB
    const int tid  = threadIdx.x;
    const int row0 = blockIdx.x * TM;

    for (int i = tid; i < TM * DD; i += NT)
        y_s[i] = y[(size_t)row0 * DD + i];
    __syncthreads();

    if (tid < DD) {
        float acc[TM];
        #pragma unroll
        for (int r = 0; r < TM; ++r) acc[r] = 0.f;
        #pragma unroll 2
        for (int e = 0; e < DD; ++e) {
            const float m = M_w[(size_t)e * DD + tid];
            #pragma unroll
            for (int r = 0; r < TM; ++r) acc[r] += m * y_s[r * DD + e];  // LDS broadcast
        }
        #pragma unroll
        for (int r = 0; r < TM; ++r)
            u[(size_t)(row0 + r) * DD + tid] = acc[r];
    }
}

// ---------------- K3: stage emb rows in LDS, then esc/softmax/z/p/r ----------------
__global__ __launch_bounds__(NT) void k_rest(
    const float* __restrict__ emb,
    const float* __restrict__ W_w,    // [K, D]
    const float* __restrict__ T_w,    // [D, K]
    const int*   __restrict__ tokens,
    const int*   __restrict__ seg_starts,
    const int*   __restrict__ seg_lens,
    const float* __restrict__ u,      // [4096, D]
    float* __restrict__ out_z,
    float* __restrict__ out_p,
    float* __restrict__ out_r)
{
    __shared__ float e_s[LL * DD];    // 76.8 KB: staged embedding rows
    __shared__ float u_s[DD];
    __shared__ float z_s[DD];
    __shared__ float a_s[LL];
    __shared__ float p_s[KK];
    __shared__ int   tok_s[LL];

    const int tid  = threadIdx.x;
    const int wave = tid >> 6;
    const int lane = tid & 63;
    const int seg  = blockIdx.x;
    const int b    = seg >> 7;
    const int start = seg_starts[seg];     // uniform
    const int len   = seg_lens[seg];

    if (tid < LL) tok_s[tid] = tokens[b * SS + start + tid];
    if (tid < DD) u_s[tid] = u[(size_t)seg * DD + tid];
    __syncthreads();

    // ---- stage len*D floats, fully coalesced, high MLP ----
    const int tot = len * DD;
    #pragma unroll 4
    for (int i = tid; i < tot; i += NT) {
        const int l = i / DD;              // const-div -> magic mul
        const int c = i - l * DD;
        e_s[i] = emb[(size_t)tok_s[l] * DD + c];
    }
    __syncthreads();

    // ---- esc[l] = dot(row_l, u), wave-per-row ----
    for (int l = wave; l < len; l += NT / 64) {
        float acc = 0.f;
        #pragma unroll
        for (int c = lane; c < DD; c += 64)
            acc += e_s[l * DD + c] * u_s[c];
        acc = wave_sum(acc);
        if (lane == 0) a_s[l] = acc;
    }
    __syncthreads();

    // ---- softmax over l (wave 0) ----
    if (wave == 0) {
        const float v = (lane < len) ? a_s[lane] : -INFINITY;
        const float mx = wave_max(v);
        const float e  = (lane < len) ? __expf(v - mx) : 0.f;
        const float sum = wave_sum(e);
        a_s[lane] = e / sum;               // 0 for padded lanes
    }
    __syncthreads();

    // ---- z[d] = sum_l alpha[l] * row_l[d] ----
    if (tid < DD) {
        float acc = 0.f;
        #pragma unroll 4
        for (int l = 0; l < len; ++l)
            acc += a_s[l] * e_s[l * DD + tid];
        z_s[tid] = acc;
        out_z[(size_t)seg * DD + tid] = acc;
    }
    __syncthreads();

    // ---- raw topic scores: wave-per-k ----
    for (int k = wave; k < KK; k += NT / 64) {
        float acc = 0.f;
        #pragma unroll
        for (int c = lane; c < DD; c += 64)
            acc += W_w[(size_t)k * DD + c] * z_s[c];
        acc = wave_sum(acc);
        if (lane == 0) p_s[k] = acc;
    }
    __syncthreads();

    // ---- softmax over k (wave 0), write p ----
    if (wave == 0) {
        const float v = (lane < KK) ? p_s[lane] : -INFINITY;
        const float mx = wave_max(v);
        const float e  = (lane < KK) ? __expf(v - mx) : 0.f;
        const float sum = wave_sum(e);
        if (lane < KK) {
            const float p = e / sum;
            p_s[lane] = p;
            out_p[(size_t)seg * KK + lane] = p;
        }
    }
    __syncthreads();

    // ---- r[d] = sum_k p[k] * T_w[d,k] ----
    if (tid < DD) {
        const float* trow = T_w + (size_t)tid * KK;
        float acc = 0.f;
        #pragma unroll
        for (int k = 0; k < KK; ++k) acc += p_s[k] * trow[k];
        out_r[(size_t)seg * DD + tid] = acc;
    }
}

extern "C" void kernel_launch(void* const* d_in, const int* in_sizes, int n_in,
                              void* d_out, int out_size, void* d_ws, size_t ws_size,
                              hipStream_t stream) {
    const float* emb        = (const float*)d_in[0];
    const float* M_w        = (const float*)d_in[1];
    const float* W_w        = (const float*)d_in[2];
    const float* T_w        = (const float*)d_in[3];
    const int*   tokens     = (const int*)d_in[4];
    const int*   seg_starts = (const int*)d_in[5];
    const int*   seg_lens   = (const int*)d_in[6];

    float* out   = (float*)d_out;
    float* out_y = out;                                    // [B*N*D]
    float* out_z = out + (size_t)BB * NN * DD;             // [B*N*D]
    float* out_p = out + (size_t)2 * BB * NN * DD;         // [B*N*K]
    float* out_r = out + (size_t)2 * BB * NN * DD + (size_t)BB * NN * KK;

    float* u_ws = (float*)d_ws;                            // [B*N*D] = 4.9 MB

    const int nseg = BB * NN;                              // 4096

    hipLaunchKernelGGL(k_y, dim3(nseg), dim3(NT), 0, stream,
                       emb, tokens, seg_starts, seg_lens, out_y);
    hipLaunchKernelGGL(k_u, dim3(nseg / TM), dim3(NT), 0, stream,
                       out_y, M_w, u_ws);
    hipLaunchKernelGGL(k_rest, dim3(nseg), dim3(NT), 0, stream,
                       emb, W_w, T_w, tokens, seg_starts, seg_lens,
                       u_ws, out_z, out_p, out_r);
}

// Round 3
// 194.726 us; speedup vs baseline: 2.9998x; 1.6364x over previous
//
#include <hip/hip_runtime.h>

#define DD 300
#define KK 50
#define BB 32
#define SS 8192
#define NN 128
#define LL 64
#define NT 320        // 5 waves
#define NW 5          // waves per block
#define NJ 13         // max rows per wave = ceil(64/5)
#define NC 5          // 64-lane chunks per row = ceil(300/64)
#define TM 16         // rows per block in the u-GEMM

__device__ __forceinline__ float wave_sum(float v) {
    #pragma unroll
    for (int m = 32; m; m >>= 1) v += __shfl_xor(v, m, 64);
    return v;
}
__device__ __forceinline__ float wave_max(float v) {
    #pragma unroll
    for (int m = 32; m; m >>= 1) v = fmaxf(v, __shfl_xor(v, m, 64));
    return v;
}

// ---------------- K1: y = masked mean (wave-per-row, register accumulate) ----------------
__global__ __launch_bounds__(NT) void k_y(
    const float* __restrict__ emb,
    const int*   __restrict__ tokens,
    const int*   __restrict__ seg_starts,
    const int*   __restrict__ seg_lens,
    float* __restrict__ out_y)
{
    __shared__ int   tok_s[LL];
    __shared__ float part[NW][NT];    // 6.4 KB

    const int tid  = threadIdx.x;
    const int wave = tid >> 6;
    const int lane = tid & 63;
    const int seg  = blockIdx.x;
    const int b    = seg >> 7;                // N = 128
    const int start = seg_starts[seg];
    const int len   = seg_lens[seg];

    if (tid < LL) tok_s[tid] = tokens[b * SS + start + tid];
    __syncthreads();

    float acc[NC] = {0.f, 0.f, 0.f, 0.f, 0.f};
    #pragma unroll
    for (int j = 0; j < NJ; ++j) {
        const int l = wave + j * NW;
        if (l < len) {                         // wave-uniform predicate
            const float* row = emb + (size_t)tok_s[l] * DD;
            #pragma unroll
            for (int c = 0; c < NC - 1; ++c) acc[c] += row[lane + 64 * c];
            if (lane < DD - 256) acc[NC - 1] += row[lane + 256];
        }
    }
    #pragma unroll
    for (int c = 0; c < NC; ++c) part[wave][lane + 64 * c] = acc[c];
    __syncthreads();

    if (tid < DD) {
        float s = part[0][tid] + part[1][tid] + part[2][tid] + part[3][tid] + part[4][tid];
        out_y[(size_t)seg * DD + tid] = s / (float)len;
    }
}

// ---------------- K2: u[seg,d] = sum_e y[seg,e] * M_w[e,d]  (TM rows/block) ----------------
__global__ __launch_bounds__(NT) void k_u(
    const float* __restrict__ y,      // [4096, D]
    const float* __restrict__ M_w,    // [D, D]
    float* __restrict__ u)            // [4096, D]
{
    __shared__ float y_s[TM * DD];    // 19.2 KB
    const int tid  = threadIdx.x;
    const int row0 = blockIdx.x * TM;

    for (int i = tid; i < TM * DD; i += NT)
        y_s[i] = y[(size_t)row0 * DD + i];
    __syncthreads();

    if (tid < DD) {
        float acc[TM];
        #pragma unroll
        for (int r = 0; r < TM; ++r) acc[r] = 0.f;
        #pragma unroll 2
        for (int e = 0; e < DD; ++e) {
            const float m = M_w[(size_t)e * DD + tid];
            #pragma unroll
            for (int r = 0; r < TM; ++r) acc[r] += m * y_s[r * DD + e];  // LDS broadcast
        }
        #pragma unroll
        for (int r = 0; r < TM; ++r)
            u[(size_t)(row0 + r) * DD + tid] = acc[r];
    }
}

// ---------------- K3: rows in registers -> esc, softmax, z, p, r ----------------
__global__ __launch_bounds__(NT) void k_rest(
    const float* __restrict__ emb,
    const float* __restrict__ W_w,    // [K, D]
    const float* __restrict__ T_w,    // [D, K]
    const int*   __restrict__ tokens,
    const int*   __restrict__ seg_starts,
    const int*   __restrict__ seg_lens,
    const float* __restrict__ u,      // [4096, D]
    float* __restrict__ out_z,
    float* __restrict__ out_p,
    float* __restrict__ out_r)
{
    __shared__ int   tok_s[LL];
    __shared__ float u_s[NT];         // padded to 320, zeros past 300
    __shared__ float a_s[LL];
    __shared__ float zp_s[NW][NT];    // per-wave z partials, 6.4 KB
    __shared__ float z_s[NT];
    __shared__ float p_s[64];

    const int tid  = threadIdx.x;
    const int wave = tid >> 6;
    const int lane = tid & 63;
    const int seg  = blockIdx.x;
    const int b    = seg >> 7;
    const int start = seg_starts[seg];
    const int len   = seg_lens[seg];

    if (tid < LL) tok_s[tid] = tokens[b * SS + start + tid];
    u_s[tid] = (tid < DD) ? u[(size_t)seg * DD + tid] : 0.f;
    __syncthreads();

    // ---- load this wave's rows into registers + esc dot ----
    float rr[NJ][NC];
    #pragma unroll
    for (int j = 0; j < NJ; ++j) {
        const int l = wave + j * NW;
        const bool live = (l < len);          // wave-uniform
        #pragma unroll
        for (int c = 0; c < NC; ++c) rr[j][c] = 0.f;
        if (live) {
            const float* row = emb + (size_t)tok_s[l] * DD;
            #pragma unroll
            for (int c = 0; c < NC - 1; ++c) rr[j][c] = row[lane + 64 * c];
            if (lane < DD - 256) rr[j][NC - 1] = row[lane + 256];
        }
        float dot = 0.f;
        #pragma unroll
        for (int c = 0; c < NC; ++c) dot += rr[j][c] * u_s[lane + 64 * c];
        dot = wave_sum(dot);
        if (live && lane == 0) a_s[l] = dot;
    }
    __syncthreads();

    // ---- softmax over l (wave 0), alpha -> a_s (0 for pads) ----
    if (wave == 0) {
        const float v  = (lane < len) ? a_s[lane] : -INFINITY;
        const float mx = wave_max(v);
        const float e  = (lane < len) ? __expf(v - mx) : 0.f;
        const float sm = wave_sum(e);
        a_s[lane] = e / sm;
    }
    __syncthreads();

    // ---- z partial from registers ----
    {
        float zacc[NC] = {0.f, 0.f, 0.f, 0.f, 0.f};
        #pragma unroll
        for (int j = 0; j < NJ; ++j) {
            const int l = wave + j * NW;
            if (l < len) {
                const float a = a_s[l];       // broadcast
                #pragma unroll
                for (int c = 0; c < NC; ++c) zacc[c] += a * rr[j][c];
            }
        }
        #pragma unroll
        for (int c = 0; c < NC; ++c) zp_s[wave][lane + 64 * c] = zacc[c];
    }
    __syncthreads();

    // ---- combine z, write out ----
    {
        const float zv = (tid < DD)
            ? zp_s[0][tid] + zp_s[1][tid] + zp_s[2][tid] + zp_s[3][tid] + zp_s[4][tid]
            : 0.f;
        z_s[tid] = zv;
        if (tid < DD) out_z[(size_t)seg * DD + tid] = zv;
    }
    __syncthreads();

    // ---- raw topic scores: wave-per-k ----
    for (int k = wave; k < KK; k += NW) {
        const float* row = W_w + (size_t)k * DD;
        float acc = 0.f;
        #pragma unroll
        for (int c = 0; c < NC - 1; ++c) acc += row[lane + 64 * c] * z_s[lane + 64 * c];
        if (lane < DD - 256) acc += row[lane + 256] * z_s[lane + 256];
        acc = wave_sum(acc);
        if (lane == 0) p_s[k] = acc;
    }
    __syncthreads();

    // ---- softmax over k (wave 0), write p ----
    if (wave == 0) {
        const float v  = (lane < KK) ? p_s[lane] : -INFINITY;
        const float mx = wave_max(v);
        const float e  = (lane < KK) ? __expf(v - mx) : 0.f;
        const float sm = wave_sum(e);
        if (lane < KK) {
            const float p = e / sm;
            p_s[lane] = p;
            out_p[(size_t)seg * KK + lane] = p;
        }
    }
    __syncthreads();

    // ---- r[d] = sum_k p[k] * T_w[d,k] ----
    if (tid < DD) {
        const float* trow = T_w + (size_t)tid * KK;
        float acc = 0.f;
        #pragma unroll
        for (int k = 0; k < KK; ++k) acc += p_s[k] * trow[k];
        out_r[(size_t)seg * DD + tid] = acc;
    }
}

extern "C" void kernel_launch(void* const* d_in, const int* in_sizes, int n_in,
                              void* d_out, int out_size, void* d_ws, size_t ws_size,
                              hipStream_t stream) {
    const float* emb        = (const float*)d_in[0];
    const float* M_w        = (const float*)d_in[1];
    const float* W_w        = (const float*)d_in[2];
    const float* T_w        = (const float*)d_in[3];
    const int*   tokens     = (const int*)d_in[4];
    const int*   seg_starts = (const int*)d_in[5];
    const int*   seg_lens   = (const int*)d_in[6];

    float* out   = (float*)d_out;
    float* out_y = out;                                    // [B*N*D]
    float* out_z = out + (size_t)BB * NN * DD;             // [B*N*D]
    float* out_p = out + (size_t)2 * BB * NN * DD;         // [B*N*K]
    float* out_r = out + (size_t)2 * BB * NN * DD + (size_t)BB * NN * KK;

    float* u_ws = (float*)d_ws;                            // [B*N*D] = 4.9 MB

    const int nseg = BB * NN;                              // 4096

    hipLaunchKernelGGL(k_y, dim3(nseg), dim3(NT), 0, stream,
                       emb, tokens, seg_starts, seg_lens, out_y);
    hipLaunchKernelGGL(k_u, dim3(nseg / TM), dim3(NT), 0, stream,
                       out_y, M_w, u_ws);
    hipLaunchKernelGGL(k_rest, dim3(nseg), dim3(NT), 0, stream,
                       emb, W_w, T_w, tokens, seg_starts, seg_lens,
                       u_ws, out_z, out_p, out_r);
}